// Round 4
// baseline (171.865 us; speedup 1.0000x reference)
//
#include <hip/hip_runtime.h>

// B=8, C=21, H=512, W=512 ; gt/pred int32 ; output = scalar f32
// mean over B of tp / max(tp+fp+fn, 1e-8)
//   valid = gt != 255 ; eq = gt==pred ; gt_in = 1<=gt<21 ; pred_in = 1<=pred<21

#define N_CLASSES 21
#define IGNORE_LBL 255
#define BATCH 8
#define THREADS 256
#define WAVES 4
#define BLOCKS_PER_SAMPLE 256
#define VEC_PER_SAMPLE 1376256   // int4 per sample (21*512*512/4)
#define VEC_PER_BLOCK 5376       // int4 per block per stream
#define VEC_PER_WAVE 1344        // int4 per wave per stream
#define TILES 21                 // 1KB wave-tiles per stream (64 int4 each)
#define DEPTH 4                  // LDS ring depth per wave
#define TOTAL_BLOCKS (BLOCKS_PER_SAMPLE * BATCH)  // 2048

typedef __attribute__((address_space(3))) void lds_void;
typedef const __attribute__((address_space(1))) void gbl_void;

__device__ __forceinline__ void proc4(const int4& g, const int4& p,
                                      int& tp, int& fp, int& fn) {
    const int gv[4] = {g.x, g.y, g.z, g.w};
    const int pv[4] = {p.x, p.y, p.z, p.w};
#pragma unroll
    for (int k = 0; k < 4; ++k) {
        const int gk = gv[k], pk = pv[k];
        const int valid = (gk != IGNORE_LBL);
        const int eq = (gk == pk);
        const int gin = (gk >= 1) & (gk < N_CLASSES);
        const int pin = (pk >= 1) & (pk < N_CLASSES);
        tp += eq & gin & valid;
        fp += (eq ^ 1) & pin & valid;
        fn += (eq ^ 1) & gin & valid;
    }
}

// ws layout: u32 counts[BATCH*3] then u32 done_counter
__global__ __launch_bounds__(THREADS) void iou_fused_kernel(
    const int* __restrict__ gt, const int* __restrict__ pred,
    unsigned int* __restrict__ ws, float* __restrict__ out) {
    // per-wave private ring: [wave][slot][stream(g/p)][64 int4] = 32 KB total
    __shared__ int4 smem[WAVES][DEPTH][2][64];

    const int blk = blockIdx.x;
    const int b = blk >> 8;
    const int seg = blk & 255;
    const int w = threadIdx.x >> 6;
    const int lane = threadIdx.x & 63;

    const size_t base = (size_t)b * VEC_PER_SAMPLE + (size_t)seg * VEC_PER_BLOCK
                        + (size_t)w * VEC_PER_WAVE + lane;
    const int4* __restrict__ g4 = reinterpret_cast<const int4*>(gt) + base;
    const int4* __restrict__ p4 = reinterpret_cast<const int4*>(pred) + base;

    // prologue: fill the ring (8 wave-loads = 8 KB in flight per wave)
#pragma unroll
    for (int t = 0; t < DEPTH; ++t) {
        __builtin_amdgcn_global_load_lds((gbl_void*)(g4 + t * 64),
                                         (lds_void*)&smem[w][t][0][0], 16, 0, 0);
        __builtin_amdgcn_global_load_lds((gbl_void*)(p4 + t * 64),
                                         (lds_void*)&smem[w][t][1][0], 16, 0, 0);
    }

    int tp = 0, fp = 0, fn = 0;

    // main loop: counted vmcnt(6) keeps 3 tile-pairs in flight at all times
#pragma unroll
    for (int t = 0; t < 18; ++t) {
        asm volatile("s_waitcnt vmcnt(6)" ::: "memory");
        int4 g = smem[w][t & 3][0][lane];
        int4 p = smem[w][t & 3][1][lane];
        proc4(g, p, tp, fp, fn);
        __builtin_amdgcn_sched_barrier(0);  // don't hoist refill above consume
        if (t <= 16) {
            __builtin_amdgcn_global_load_lds((gbl_void*)(g4 + (t + DEPTH) * 64),
                                             (lds_void*)&smem[w][t & 3][0][0], 16, 0, 0);
            __builtin_amdgcn_global_load_lds((gbl_void*)(p4 + (t + DEPTH) * 64),
                                             (lds_void*)&smem[w][t & 3][1][0], 16, 0, 0);
        }
    }
    // epilogue: tiles 18,19,20 in slots 2,3,0 ; drain 4 -> 2 -> 0
    {
        asm volatile("s_waitcnt vmcnt(4)" ::: "memory");
        int4 g = smem[w][2][0][lane];
        int4 p = smem[w][2][1][lane];
        proc4(g, p, tp, fp, fn);
        asm volatile("s_waitcnt vmcnt(2)" ::: "memory");
        g = smem[w][3][0][lane];
        p = smem[w][3][1][lane];
        proc4(g, p, tp, fp, fn);
        asm volatile("s_waitcnt vmcnt(0)" ::: "memory");
        g = smem[w][0][0][lane];
        p = smem[w][0][1][lane];
        proc4(g, p, tp, fp, fn);
    }

    // wave (64-lane) reduce
#pragma unroll
    for (int off = 32; off > 0; off >>= 1) {
        tp += __shfl_down(tp, off);
        fp += __shfl_down(fp, off);
        fn += __shfl_down(fn, off);
    }

    __shared__ int s_tp[WAVES], s_fp[WAVES], s_fn[WAVES];
    if (lane == 0) {
        s_tp[w] = tp;
        s_fp[w] = fp;
        s_fn[w] = fn;
    }
    __syncthreads();

    if (threadIdx.x == 0) {
        int t = 0, f = 0, n = 0;
#pragma unroll
        for (int wv = 0; wv < WAVES; ++wv) {
            t += s_tp[wv];
            f += s_fp[wv];
            n += s_fn[wv];
        }
        atomicAdd(&ws[b * 3 + 0], (unsigned int)t);
        atomicAdd(&ws[b * 3 + 1], (unsigned int)f);
        atomicAdd(&ws[b * 3 + 2], (unsigned int)n);

        // last-block finalize (device-scope atomics; coherent across XCDs)
        __threadfence();
        const unsigned int prev = atomicAdd(&ws[BATCH * 3], 1u);
        if (prev == TOTAL_BLOCKS - 1) {
            __threadfence();
            float s = 0.0f;
#pragma unroll
            for (int bb = 0; bb < BATCH; ++bb) {
                const float tpf = (float)atomicAdd(&ws[bb * 3 + 0], 0u);
                const float fpf = (float)atomicAdd(&ws[bb * 3 + 1], 0u);
                const float fnf = (float)atomicAdd(&ws[bb * 3 + 2], 0u);
                s += tpf / fmaxf(tpf + fpf + fnf, 1e-8f);
            }
            out[0] = s / (float)BATCH;
        }
    }
}

extern "C" void kernel_launch(void* const* d_in, const int* in_sizes, int n_in,
                              void* d_out, int out_size, void* d_ws, size_t ws_size,
                              hipStream_t stream) {
    const int* gt = (const int*)d_in[0];
    const int* pred = (const int*)d_in[1];
    float* out = (float*)d_out;
    unsigned int* ws = (unsigned int*)d_ws;

    hipMemsetAsync(ws, 0, (BATCH * 3 + 1) * sizeof(unsigned int), stream);

    dim3 grid(TOTAL_BLOCKS, 1, 1);
    dim3 block(THREADS, 1, 1);
    iou_fused_kernel<<<grid, block, 0, stream>>>(gt, pred, ws, out);
}

// Round 5
// 86.315 us; speedup vs baseline: 1.9911x; 1.9911x over previous
//
#include <hip/hip_runtime.h>

// B=8, C=21, H=512, W=512 ; gt/pred int32 ; output = scalar f32
// mean over B of tp / max(tp+fp+fn, 1e-8)
//   valid = gt != 255 ; eq = gt==pred ; gt_in = 1<=gt<21 ; pred_in = 1<=pred<21

#define N_CLASSES 21
#define IGNORE_LBL 255
#define BATCH 8
#define BPS 256                  // blocks per sample
#define THREADS 256
#define VEC_PER_SAMPLE 1376256   // int4 per sample (21*512*512/4)
#define STRIDE (BPS * THREADS)   // 65536 int4 = 1 MB

__device__ __forceinline__ void proc4(const int4& g, const int4& p,
                                      int& tp, int& fp, int& fn) {
    const int gv[4] = {g.x, g.y, g.z, g.w};
    const int pv[4] = {p.x, p.y, p.z, p.w};
#pragma unroll
    for (int k = 0; k < 4; ++k) {
        const int gk = gv[k], pk = pv[k];
        const int valid = (gk != IGNORE_LBL);
        const int eq = (gk == pk);
        const int gin = (gk >= 1) & (gk < N_CLASSES);
        const int pin = (pk >= 1) & (pk < N_CLASSES);
        tp += eq & gin & valid;
        fp += (eq ^ 1) & pin & valid;
        fn += (eq ^ 1) & gin & valid;
    }
}

// counts padded: sample b at counts[b*8 + {0,1,2}] (32 B apart)
__global__ __launch_bounds__(THREADS) void iou_count_kernel(
    const int* __restrict__ gt, const int* __restrict__ pred,
    unsigned int* __restrict__ counts) {
    const int b = blockIdx.y;
    const int4* __restrict__ g4 =
        reinterpret_cast<const int4*>(gt) + (size_t)b * VEC_PER_SAMPLE;
    const int4* __restrict__ p4 =
        reinterpret_cast<const int4*>(pred) + (size_t)b * VEC_PER_SAMPLE;

    int i = blockIdx.x * THREADS + threadIdx.x;
    int tp = 0, fp = 0, fn = 0;

    // 21 iters = 10 x unroll2 + 1 tail. Named loads + sched_barrier(0)
    // force all 4 loads issued before any consume (real MLP; no wave cap
    // so the allocator has register headroom).
#pragma unroll
    for (int u = 0; u < 10; ++u) {
        const int4 g0 = g4[i];
        const int4 p0 = p4[i];
        const int4 g1 = g4[i + STRIDE];
        const int4 p1 = p4[i + STRIDE];
        __builtin_amdgcn_sched_barrier(0);
        proc4(g0, p0, tp, fp, fn);
        proc4(g1, p1, tp, fp, fn);
        i += 2 * STRIDE;
    }
    {
        const int4 g = g4[i];
        const int4 p = p4[i];
        proc4(g, p, tp, fp, fn);
    }

    // wave (64-lane) reduce
#pragma unroll
    for (int off = 32; off > 0; off >>= 1) {
        tp += __shfl_down(tp, off);
        fp += __shfl_down(fp, off);
        fn += __shfl_down(fn, off);
    }

    __shared__ int s_tp[4], s_fp[4], s_fn[4];  // 256 threads = 4 waves
    const int wave = threadIdx.x >> 6;
    const int lane = threadIdx.x & 63;
    if (lane == 0) {
        s_tp[wave] = tp;
        s_fp[wave] = fp;
        s_fn[wave] = fn;
    }
    __syncthreads();
    if (threadIdx.x == 0) {
        int t = 0, f = 0, n = 0;
#pragma unroll
        for (int w = 0; w < 4; ++w) {
            t += s_tp[w];
            f += s_fp[w];
            n += s_fn[w];
        }
        // device-scope atomics, NO threadfence (fence = L2 flush = r2-r4 regression)
        atomicAdd(&counts[b * 8 + 0], (unsigned int)t);
        atomicAdd(&counts[b * 8 + 1], (unsigned int)f);
        atomicAdd(&counts[b * 8 + 2], (unsigned int)n);
    }
}

__global__ void iou_final_kernel(const unsigned int* __restrict__ counts,
                                 float* __restrict__ out) {
    if (threadIdx.x == 0 && blockIdx.x == 0) {
        float s = 0.0f;
#pragma unroll
        for (int b = 0; b < BATCH; ++b) {
            const float tp = (float)counts[b * 8 + 0];
            const float fp = (float)counts[b * 8 + 1];
            const float fn = (float)counts[b * 8 + 2];
            s += tp / fmaxf(tp + fp + fn, 1e-8f);
        }
        out[0] = s / (float)BATCH;
    }
}

extern "C" void kernel_launch(void* const* d_in, const int* in_sizes, int n_in,
                              void* d_out, int out_size, void* d_ws, size_t ws_size,
                              hipStream_t stream) {
    const int* gt = (const int*)d_in[0];
    const int* pred = (const int*)d_in[1];
    float* out = (float*)d_out;
    unsigned int* counts = (unsigned int*)d_ws;  // BATCH*8 u32, padded

    hipMemsetAsync(counts, 0, BATCH * 8 * sizeof(unsigned int), stream);

    dim3 grid(BPS, BATCH, 1);
    dim3 block(THREADS, 1, 1);
    iou_count_kernel<<<grid, block, 0, stream>>>(gt, pred, counts);
    iou_final_kernel<<<1, 64, 0, stream>>>(counts, out);
}